// Round 5
// baseline (395.381 us; speedup 1.0000x reference)
//
#include <hip/hip_runtime.h>

// Problem constants: images (16,3,768,768) f32, h=w=48, N=2304,
// SIGMA_COLOR=0.1 -> exp(-50*cd), SIGMA_SPATIAL=5 -> exp(-0.02*sd), RADIUS=8.
#define BATCH 16
#define CH    3
#define HIN   768
#define WIN   768
#define HS    48
#define WS    48
#define NPIX  (HS * WS)          // 2304
#define QPR   (NPIX / 4)         // 576 float4 quads per output row

typedef float f32x4 __attribute__((ext_vector_type(4)));

// Kernel 1: bilinear downsample 768->48 (half-pixel centers, scale 16).
// Sample coord 16*i + 7.5 -> exact 2x2 average of pixels {16i+7, 16i+8}.
__global__ void downsample_kernel(const float* __restrict__ img,
                                  f32x4* __restrict__ feats) {
    int idx = blockIdx.x * blockDim.x + threadIdx.x;   // over BATCH*NPIX = 36864
    if (idx >= BATCH * NPIX) return;
    int b = idx / NPIX;
    int n = idx - b * NPIX;
    int y = n / WS;
    int x = n - y * WS;
    int iy = 16 * y + 7;
    int ix = 16 * x + 7;
    const float* base = img + (size_t)b * CH * HIN * WIN;
    float f[3];
#pragma unroll
    for (int c = 0; c < 3; ++c) {
        const float* p = base + (size_t)c * HIN * WIN;
        const float* r0 = p + (size_t)iy * WIN + ix;
        const float* r1 = r0 + WIN;
        f[c] = 0.25f * (r0[0] + r0[1] + r1[0] + r1[1]);
    }
    f32x4 v = {f[0], f[1], f[2], 0.0f};
    feats[idx] = v;
}

// Kernel 2: one block per (b, yi) stripe = 48 complete output rows.
// The nonzero j-band [12*(yi-8), 12*(yi+9)) is block-uniform, contiguous,
// and <= 204 quads wide (< 256), so each thread's 3 j-slots (tid, tid+256,
// tid+512) contain AT MOST ONE band quad. That quad's metadata + fj loads
// are hoisted out of the 48-row loop. Inner loop: 48 x 3 dense predicated
// float4 stores per thread (~144 stores/thread, fill-kernel-like density).
__global__ __launch_bounds__(256) void affinity_kernel(const f32x4* __restrict__ feats,
                                                       f32x4* __restrict__ out) {
    const int tid = threadIdx.x;                 // 0..255
    const int yi  = blockIdx.x;                  // 0..47
    const int b   = blockIdx.y;                  // 0..15
    const int i0  = yi * WS;                     // first row of the stripe

    const f32x4* __restrict__ frow  = feats + b * NPIX;
    f32x4* __restrict__       obase = out + (size_t)(b * NPIX + i0) * QPR;

    const int ylo = (yi - 8 > 0) ? yi - 8 : 0;
    const int yhi = (yi + 8 < HS - 1) ? yi + 8 : HS - 1;
    const int qlo = 12 * ylo;                    // band start (quad units)
    const int qhi = 12 * (yhi + 1);              // band end; width 108..204

    // Find this thread's (unique, if any) band slot; hoist its metadata.
    int slot = -1, xj0 = 0;
    float sdy = 0.0f;
    f32x4 fj0 = {0,0,0,0}, fj1 = {0,0,0,0}, fj2 = {0,0,0,0}, fj3 = {0,0,0,0};
#pragma unroll
    for (int s = 0; s < 3; ++s) {
        const int q = tid + 256 * s;
        if (q < QPR && q >= qlo && q < qhi) slot = s;
    }
    if (slot >= 0) {
        const int q  = tid + 256 * slot;
        const int yj = q / 12;                   // once per block, not per store
        const int dy = yi - yj;                  // |dy| <= 8 by construction
        sdy = (float)(dy * dy);
        xj0 = (q - yj * 12) * 4;
        fj0 = frow[4 * q + 0];
        fj1 = frow[4 * q + 1];
        fj2 = frow[4 * q + 2];
        fj3 = frow[4 * q + 3];
    }

    const f32x4 z = {0.f, 0.f, 0.f, 0.f};
#pragma unroll 1
    for (int ii = 0; ii < WS; ++ii) {            // 48 rows; xi == ii
        const f32x4 fi = frow[i0 + ii];
        f32x4* __restrict__ orow = obase + (size_t)ii * QPR;
#pragma unroll
        for (int s = 0; s < 3; ++s) {
            if (s < 2 || tid < QPR - 512) {      // slot 2 valid only for tid<64
                f32x4 r = z;
                if (s == slot) {
                    const f32x4 fjv[4] = {fj0, fj1, fj2, fj3};
#pragma unroll
                    for (int k = 0; k < 4; ++k) {
                        const int   dx = ii - (xj0 + k);
                        const float d0 = fi.x - fjv[k].x;
                        const float d1 = fi.y - fjv[k].y;
                        const float d2 = fi.z - fjv[k].z;
                        const float cd = d0 * d0 + d1 * d1 + d2 * d2;
                        const float sd = sdy + (float)(dx * dx);
                        const float e  = __expf(-50.0f * cd - 0.02f * sd);
                        r[k] = ((unsigned)(dx + 8) <= 16u) ? e : 0.0f;
                    }
                }
                orow[tid + 256 * s] = r;
            }
        }
    }
}

extern "C" void kernel_launch(void* const* d_in, const int* in_sizes, int n_in,
                              void* d_out, int out_size, void* d_ws, size_t ws_size,
                              hipStream_t stream) {
    const float* img = (const float*)d_in[0];
    f32x4* feats = (f32x4*)d_ws;                   // 16*2304*16 B = 589,824 B
    f32x4* out   = (f32x4*)d_out;

    {
        int threads = BATCH * NPIX;                // 36,864
        int block = 256;
        int grid = (threads + block - 1) / block;  // 144
        downsample_kernel<<<grid, block, 0, stream>>>(img, feats);
    }
    {
        dim3 grid(HS, BATCH);                      // (48, 16) = 768 blocks
        affinity_kernel<<<grid, 256, 0, stream>>>(feats, out);
    }
}